// Round 11
// baseline (236.518 us; speedup 1.0000x reference)
//
#include <hip/hip_runtime.h>

#define NNODES 50000
#define NEDGES 800000
#define HIDDIM 256
#define NB_SCAN 196   // ceil(NNODES/256)
#define FILLB   256   // fill blocks appended to gemm1 grid

constexpr float kAlpha = 0.1f;
constexpr float kBnEps = 1e-5f;
constexpr float kBeta  = 0.40546510810816438198f;   // log(1.5)

typedef __attribute__((ext_vector_type(8))) short  bf16x8;   // 8 bf16 in 4 VGPRs
typedef __attribute__((ext_vector_type(4))) float  f32x4;

typedef __attribute__((address_space(1))) const unsigned int gu32;  // global
typedef __attribute__((address_space(3))) unsigned int       lu32;  // LDS

static __device__ __forceinline__ unsigned short f2bf(float f) {
  unsigned u = __float_as_uint(f);
  u = (u + 0x7FFFu + ((u >> 16) & 1u)) >> 16;      // RTNE
  return (unsigned short)u;
}
static __device__ __forceinline__ float bf2f(unsigned short h) {
  return __uint_as_float(((unsigned)h) << 16);
}

// ---------------------------------------------------------------------------
// prep (blocks 0..511): weight transposes + zero BN stats
// hist (blocks 512..): degree histogram over edge dst (int4 vectorized)
// deg[] and scan-status[] zeroed by a preceding hipMemsetAsync.
// ---------------------------------------------------------------------------
__global__ __launch_bounds__(256) void prep_hist_k(const float* __restrict__ W_pre,
                                                   const float* __restrict__ W_op,
                                                   unsigned short* __restrict__ wpre_t,
                                                   unsigned short* __restrict__ wop_t,
                                                   float* __restrict__ colsum,
                                                   float* __restrict__ colsumsq,
                                                   const int* __restrict__ ei,
                                                   int* __restrict__ deg) {
  const int b = blockIdx.x, t = threadIdx.x;
  if (b < 256) {
    wpre_t[b * 256 + t] = f2bf(W_pre[t * 256 + b]);
    if (b == 0) { colsum[t] = 0.f; colsumsq[t] = 0.f; }
  } else if (b < 512) {
    int n = b - 256;
    wop_t[n * 256 + t] = f2bf(W_op[t * 256 + n]);
  } else {
    const int4* dst4 = (const int4*)(ei + NEDGES);
    const int n4 = NEDGES / 4;
    const int nb = gridDim.x - 512;
    for (int i = (b - 512) * 256 + t; i < n4; i += nb * 256) {
      int4 d = dst4[i];
      atomicAdd(&deg[d.x], 1);
      atomicAdd(&deg[d.y], 1);
      atomicAdd(&deg[d.z], 1);
      atomicAdd(&deg[d.w], 1);
    }
  }
}

// ---------------------------------------------------------------------------
// Single-dispatch exclusive scan (decoupled lookback; 196 blocks, all
// co-resident on 256 CUs -> no scheduling deadlock). Writes rowptr and
// seeds cursor. status[] pre-zeroed (0=invalid, 1=aggregate, 2=inclusive).
// ---------------------------------------------------------------------------
__global__ __launch_bounds__(256) void scan_k(const int* __restrict__ deg,
                                              int* __restrict__ rowptr,
                                              int* __restrict__ cursor,
                                              int* __restrict__ aggv,
                                              int* __restrict__ inclv,
                                              int* __restrict__ status) {
  __shared__ int sh[256];
  __shared__ int s_prefix;
  const int b = blockIdx.x, t = threadIdx.x;
  const int idx = b * 256 + t;
  int v = (idx < NNODES) ? deg[idx] : 0;
  sh[t] = v;
  __syncthreads();
  for (int off = 1; off < 256; off <<= 1) {
    int x = (t >= off) ? sh[t - off] : 0;
    __syncthreads();
    sh[t] += x;
    __syncthreads();
  }
  const int total = sh[255];
  if (t == 0) {
    __hip_atomic_store(&aggv[b], total, __ATOMIC_RELAXED, __HIP_MEMORY_SCOPE_AGENT);
    __hip_atomic_store(&status[b], 1, __ATOMIC_RELEASE, __HIP_MEMORY_SCOPE_AGENT);
    int prefix = 0;
    for (int p = b - 1; p >= 0; --p) {
      int st;
      do { st = __hip_atomic_load(&status[p], __ATOMIC_ACQUIRE, __HIP_MEMORY_SCOPE_AGENT); } while (st == 0);
      if (st == 2) {
        prefix += __hip_atomic_load(&inclv[p], __ATOMIC_RELAXED, __HIP_MEMORY_SCOPE_AGENT);
        break;
      }
      prefix += __hip_atomic_load(&aggv[p], __ATOMIC_RELAXED, __HIP_MEMORY_SCOPE_AGENT);
    }
    __hip_atomic_store(&inclv[b], prefix + total, __ATOMIC_RELAXED, __HIP_MEMORY_SCOPE_AGENT);
    __hip_atomic_store(&status[b], 2, __ATOMIC_RELEASE, __HIP_MEMORY_SCOPE_AGENT);
    s_prefix = prefix;
    if (b == NB_SCAN - 1) rowptr[NNODES] = prefix + total;   // = NEDGES
  }
  __syncthreads();
  if (idx < NNODES) {
    int excl = s_prefix + sh[t] - v;
    rowptr[idx] = excl;
    cursor[idx] = excl;
  }
}

// ---------------------------------------------------------------------------
// bf16 MFMA GEMM body: C = A[M,256] @ B[256,256], Bt transposed [n][k].
// 128x256 tile, BK=32, 8 K-steps, LDS double-buffer, one barrier per step.
// MODE 0: A fp32 (reg-staged + converted); C bf16 raw + column sum/sumsq
// MODE 1: A bf16 (global_load_lds); C fp32 = relu((1-beta)*S + beta*(A@B))
// ---------------------------------------------------------------------------
template<int MODE>
__device__ __forceinline__ void gemm_body(
    const void* __restrict__ Ain,
    const unsigned short* __restrict__ Bt,
    void* __restrict__ Cout,
    const unsigned short* __restrict__ S,
    float* __restrict__ colsum,
    float* __restrict__ colsumsq,
    int M, int bx) {
  __shared__ unsigned short Al[2][128 * 32]; // 2 x 8 KB, row stride 64 B
  __shared__ unsigned short Bl[2][256 * 32]; // 2 x 16 KB
  __shared__ float cs[4][128], cq[4][128];   // MODE0 column-stat reduction

  const int t    = threadIdx.x;
  const int lane = t & 63;
  const int wid  = t >> 6;
  const int wr   = wid >> 1;
  const int wc   = wid & 1;
  const int row0 = bx * 128;

  f32x4 acc[4][8] = {};

  const int srow = t & 127;
  const int sseg = t >> 7;
  const int arow = row0 + srow;
  const bool aok = arow < M;
  const int swzA = (srow & 3) << 4;

  const int lrow = lane >> 2;
  const int lchk = lane & 3;
  const int lsw  = (lchk * 16) ^ ((lrow & 3) << 4);

  auto stage = [&](int b, int ks) {
    const int k0 = ks * 32;
    if (MODE == 0) {
      const float* src = (const float*)Ain + (size_t)arow * 256 + k0 + sseg * 16;
      bf16x8 v0 = {}, v1 = {};
      if (aok) {
        float4 p0 = *(const float4*)(src + 0);
        float4 p1 = *(const float4*)(src + 4);
        float4 p2 = *(const float4*)(src + 8);
        float4 p3 = *(const float4*)(src + 12);
        v0[0] = (short)f2bf(p0.x); v0[1] = (short)f2bf(p0.y);
        v0[2] = (short)f2bf(p0.z); v0[3] = (short)f2bf(p0.w);
        v0[4] = (short)f2bf(p1.x); v0[5] = (short)f2bf(p1.y);
        v0[6] = (short)f2bf(p1.z); v0[7] = (short)f2bf(p1.w);
        v1[0] = (short)f2bf(p2.x); v1[1] = (short)f2bf(p2.y);
        v1[2] = (short)f2bf(p2.z); v1[3] = (short)f2bf(p2.w);
        v1[4] = (short)f2bf(p3.x); v1[5] = (short)f2bf(p3.y);
        v1[6] = (short)f2bf(p3.z); v1[7] = (short)f2bf(p3.w);
      }
      char* base = (char*)&Al[b][0] + srow * 64;
      *(bf16x8*)(base + ((sseg * 32 +  0) ^ swzA)) = v0;
      *(bf16x8*)(base + ((sseg * 32 + 16) ^ swzA)) = v1;
    } else {
#pragma unroll
      for (int c = 0; c < 2; ++c) {
        int chunk = wid * 2 + c;
        int row = chunk * 16 + lrow;
        const char* g = (const char*)Ain + ((size_t)(row0 + row) * 256 + k0) * 2 + lsw;
        char* l = (char*)&Al[b][0] + chunk * 1024 + lane * 16;
        __builtin_amdgcn_global_load_lds((gu32*)g, (lu32*)l, 16, 0, 0);
      }
    }
#pragma unroll
    for (int c = 0; c < 4; ++c) {
      int chunk = wid * 4 + c;
      int row = chunk * 16 + lrow;
      const char* g = (const char*)Bt + ((size_t)row * 256 + k0) * 2 + lsw;
      char* l = (char*)&Bl[b][0] + chunk * 1024 + lane * 16;
      __builtin_amdgcn_global_load_lds((gu32*)g, (lu32*)l, 16, 0, 0);
    }
  };

  stage(0, 0);
  __syncthreads();
  for (int ks = 0; ks < 8; ++ks) {
    const int cur = ks & 1;
    if (ks < 7) stage(cur ^ 1, ks + 1);
    const int koff = (lane >> 4) * 16;
    bf16x8 af[4], bfr[8];
#pragma unroll
    for (int m = 0; m < 4; ++m) {
      int row = wr * 64 + m * 16 + (lane & 15);
      af[m] = *(const bf16x8*)((char*)&Al[cur][0] + row * 64 + (koff ^ ((row & 3) << 4)));
    }
#pragma unroll
    for (int n = 0; n < 8; ++n) {
      int nr = wc * 128 + n * 16 + (lane & 15);
      bfr[n] = *(const bf16x8*)((char*)&Bl[cur][0] + nr * 64 + (koff ^ ((nr & 3) << 4)));
    }
#pragma unroll
    for (int m = 0; m < 4; ++m)
#pragma unroll
      for (int n = 0; n < 8; ++n)
        acc[m][n] = __builtin_amdgcn_mfma_f32_16x16x32_bf16(af[m], bfr[n], acc[m][n], 0, 0, 0);
    __syncthreads();
  }

  if (MODE == 0) {
#pragma unroll
    for (int n = 0; n < 8; ++n) {
      float s = 0.f, q = 0.f;
#pragma unroll
      for (int m = 0; m < 4; ++m)
#pragma unroll
        for (int r = 0; r < 4; ++r) {
          float v = acc[m][n][r];
          s += v; q += v * v;
        }
      s += __shfl_xor(s, 16); s += __shfl_xor(s, 32);
      q += __shfl_xor(q, 16); q += __shfl_xor(q, 32);
      if (lane < 16) { cs[wid][n * 16 + lane] = s; cq[wid][n * 16 + lane] = q; }
    }
    __syncthreads();
    {
      int wcg = t >> 7;
      int lc  = t & 127;
      atomicAdd(&colsum[t],   cs[wcg][lc] + cs[wcg + 2][lc]);
      atomicAdd(&colsumsq[t], cq[wcg][lc] + cq[wcg + 2][lc]);
    }
  }

#pragma unroll
  for (int m = 0; m < 4; ++m) {
    int rbase = row0 + wr * 64 + m * 16 + (lane >> 4) * 4;
#pragma unroll
    for (int r = 0; r < 4; ++r) {
      int row = rbase + r;
      if (row < M) {
#pragma unroll
        for (int n = 0; n < 8; ++n) {
          int col = wc * 128 + n * 16 + (lane & 15);
          float v = acc[m][n][r];
          if (MODE == 0) {
            ((unsigned short*)Cout)[(size_t)row * 256 + col] = f2bf(v);
          } else {
            float s = bf2f(S[(size_t)row * 256 + col]);
            ((float*)Cout)[(size_t)row * 256 + col] =
                fmaxf((1.f - kBeta) * s + kBeta * v, 0.f);
          }
        }
      }
    }
  }
}

// ---------------------------------------------------------------------------
// Fused: blocks [0,gx) run GEMM1 (MODE 0); blocks [gx, gx+FILLB) run CSR
// fill (independent work, hides under the GEMM).
// ---------------------------------------------------------------------------
__global__ __launch_bounds__(256) void gemm1_fill_k(
    const float* __restrict__ s1,
    const unsigned short* __restrict__ wpre_t,
    unsigned short* __restrict__ hbf,
    float* __restrict__ colsum,
    float* __restrict__ colsumsq,
    const int* __restrict__ ei,
    int* __restrict__ cursor,
    int* __restrict__ esrc,
    int gx) {
  if ((int)blockIdx.x < gx) {
    gemm_body<0>(s1, wpre_t, hbf, nullptr, colsum, colsumsq, NNODES, blockIdx.x);
    return;
  }
  const int bi = blockIdx.x - gx;
  const int4* src4 = (const int4*)ei;
  const int4* dst4 = (const int4*)(ei + NEDGES);
  const int n4 = NEDGES / 4;
  for (int i = bi * 256 + (int)threadIdx.x; i < n4; i += FILLB * 256) {
    int4 s = src4[i];
    int4 d = dst4[i];
    esrc[atomicAdd(&cursor[d.x], 1)] = s.x;
    esrc[atomicAdd(&cursor[d.y], 1)] = s.y;
    esrc[atomicAdd(&cursor[d.z], 1)] = s.z;
    esrc[atomicAdd(&cursor[d.w], 1)] = s.w;
  }
}

__global__ __launch_bounds__(256) void gemm2_k(
    const unsigned short* __restrict__ supbf,
    const unsigned short* __restrict__ wop_t,
    float* __restrict__ out) {
  gemm_body<1>(supbf, wop_t, out, supbf, nullptr, nullptr, NNODES, blockIdx.x);
}

// ---------------------------------------------------------------------------
// Gather-sum per destination node with fused BN-finalize + BN/ReLU + GCNII
// support mix. Half-wave (32 lanes x 16B) per node; shfl-broadcast indices;
// gathers unrolled x4; x0 loads / supp stores non-temporal.
// ---------------------------------------------------------------------------
__global__ __launch_bounds__(256) void agg_bn_support_k(
    const unsigned short* __restrict__ hb,
    const int* __restrict__ rowptr,
    const int* __restrict__ esrc,
    const float* __restrict__ x0,
    const float* __restrict__ colsum,
    const float* __restrict__ colsumsq,
    const float* __restrict__ gamma,
    const float* __restrict__ beta_bn,
    unsigned short* __restrict__ supp_bf) {
  __shared__ float s_sc[256], s_sh[256];
  {
    int j = threadIdx.x;
    float inv_n = 1.0f / (float)NNODES;
    float mu  = colsum[j] * inv_n;
    float var = colsumsq[j] * inv_n - mu * mu;
    float rstd = rsqrtf(var + kBnEps);
    float g = gamma[j] * rstd;
    s_sc[j] = g;
    s_sh[j] = beta_bn[j] - mu * g;
  }
  __syncthreads();

  const int hw   = threadIdx.x >> 5;
  const int lane = threadIdx.x & 31;
  const int d    = blockIdx.x * 8 + hw;
  const int off  = lane * 8;

  float sc[8], sh[8];
  *(float4*)&sc[0] = *(const float4*)(s_sc + off);
  *(float4*)&sc[4] = *(const float4*)(s_sc + off + 4);
  *(float4*)&sh[0] = *(const float4*)(s_sh + off);
  *(float4*)&sh[4] = *(const float4*)(s_sh + off + 4);

  const int beg = rowptr[d];
  const int end = rowptr[d + 1];
  float acc[8] = {0.f, 0.f, 0.f, 0.f, 0.f, 0.f, 0.f, 0.f};

  for (int bb = beg; bb < end; bb += 32) {
    int cnt = end - bb; if (cnt > 32) cnt = 32;
    int myi = esrc[bb + ((lane < cnt) ? lane : 0)];
    int u = 0;
    for (; u + 3 < cnt; u += 4) {
      int s0 = __shfl(myi, u, 32),     s1 = __shfl(myi, u + 1, 32);
      int s2 = __shfl(myi, u + 2, 32), s3 = __shfl(myi, u + 3, 32);
      bf16x8 v0 = *(const bf16x8*)(hb + (size_t)s0 * HIDDIM + off);
      bf16x8 v1 = *(const bf16x8*)(hb + (size_t)s1 * HIDDIM + off);
      bf16x8 v2 = *(const bf16x8*)(hb + (size_t)s2 * HIDDIM + off);
      bf16x8 v3 = *(const bf16x8*)(hb + (size_t)s3 * HIDDIM + off);
#pragma unroll
      for (int j = 0; j < 8; ++j) {
        acc[j] += fmaxf(fmaf(bf2f((unsigned short)v0[j]), sc[j], sh[j]), 0.f)
                + fmaxf(fmaf(bf2f((unsigned short)v1[j]), sc[j], sh[j]), 0.f)
                + fmaxf(fmaf(bf2f((unsigned short)v2[j]), sc[j], sh[j]), 0.f)
                + fmaxf(fmaf(bf2f((unsigned short)v3[j]), sc[j], sh[j]), 0.f);
      }
    }
    for (; u < cnt; ++u) {
      int s0 = __shfl(myi, u, 32);
      bf16x8 v0 = *(const bf16x8*)(hb + (size_t)s0 * HIDDIM + off);
#pragma unroll
      for (int j = 0; j < 8; ++j)
        acc[j] += fmaxf(fmaf(bf2f((unsigned short)v0[j]), sc[j], sh[j]), 0.f);
    }
  }

  bf16x8 vd = *(const bf16x8*)(hb + (size_t)d * HIDDIM + off);
  f32x4 xa = __builtin_nontemporal_load((const f32x4*)(x0 + (size_t)d * HIDDIM + off));
  f32x4 xb = __builtin_nontemporal_load((const f32x4*)(x0 + (size_t)d * HIDDIM + off + 4));
  float xs[8] = {xa.x, xa.y, xa.z, xa.w, xb.x, xb.y, xb.z, xb.w};
  bf16x8 o;
#pragma unroll
  for (int j = 0; j < 8; ++j) {
    float hv = fmaxf(fmaf(bf2f((unsigned short)vd[j]), sc[j], sh[j]), 0.f);
    o[j] = (short)f2bf((1.f - kAlpha) * (hv + acc[j]) + kAlpha * xs[j]);
  }
  __builtin_nontemporal_store(o, (bf16x8*)(supp_bf + (size_t)d * HIDDIM + off));
}

// ---------------------------------------------------------------------------
extern "C" void kernel_launch(void* const* d_in, const int* in_sizes, int n_in,
                              void* d_out, int out_size, void* d_ws, size_t ws_size,
                              hipStream_t stream) {
  // inputs: s0, s1, x_0, W_pre, gamma, beta_bn, W_op, edge_index, drop_prob, training
  const float* s1    = (const float*)d_in[1];
  const float* x0    = (const float*)d_in[2];
  const float* W_pre = (const float*)d_in[3];
  const float* gamma = (const float*)d_in[4];
  const float* betab = (const float*)d_in[5];
  const float* W_op  = (const float*)d_in[6];
  const int*   ei    = (const int*)d_in[7];
  float* out = (float*)d_out;

  const size_t NH = (size_t)NNODES * HIDDIM;            // 12.8M elements
  unsigned short* hbf   = (unsigned short*)d_ws;        // 25.6 MB (raw bf16 h)
  unsigned short* supbf = hbf + NH;                     // 25.6 MB
  float* colsum   = (float*)(supbf + NH);               // 256
  float* colsumsq = colsum + HIDDIM;
  unsigned short* wpre_t = (unsigned short*)(colsumsq + HIDDIM);  // 128 KB
  unsigned short* wop_t  = wpre_t + 65536;              // 128 KB
  int* deg      = (int*)(wop_t + 65536);                // 50000
  int* status   = deg + NNODES;                         // 256 (memset with deg)
  int* cursor   = status + 256;                         // 50000
  int* rowptr   = cursor + NNODES;                      // 50001
  int* esrc     = rowptr + (NNODES + 1);                // 800000
  int* aggv     = esrc + NEDGES;                        // 256
  int* inclv    = aggv + 256;                           // 256

  // zero deg + scan status in one memset
  hipMemsetAsync(deg, 0, (NNODES + 256) * sizeof(int), stream);

  // weight transposes + BN-stat zero + degree histogram (fused)
  prep_hist_k<<<1024, 256, 0, stream>>>(W_pre, W_op, wpre_t, wop_t,
                                        colsum, colsumsq, ei, deg);

  // single-dispatch decoupled-lookback scan (writes rowptr, seeds cursor)
  scan_k<<<NB_SCAN, 256, 0, stream>>>(deg, rowptr, cursor, aggv, inclv, status);

  // GEMM1 (+BN stats) fused with CSR fill (independent)
  const int gx = (NNODES + 127) / 128;
  gemm1_fill_k<<<gx + FILLB, 256, 0, stream>>>(s1, wpre_t, hbf, colsum, colsumsq,
                                               ei, cursor, esrc, gx);

  // gather + fused BN-finalize/BN/ReLU + support mix
  agg_bn_support_k<<<(NNODES + 7) / 8, 256, 0, stream>>>(hbf, rowptr, esrc, x0,
                                                         colsum, colsumsq, gamma, betab,
                                                         supbf);

  // GEMM2 + GCNII epilogue
  gemm2_k<<<gx, 256, 0, stream>>>(supbf, wop_t, out);
}